// Round 2
// 197.497 us; speedup vs baseline: 1.0004x; 1.0004x over previous
//
#include <hip/hip_runtime.h>
#include <math.h>

#ifndef PI_F
#define PI_F 3.14159265358979323846f
#endif

// out[i] = (-pi^2 - (P*pi)^2 + a^2) * sin(pi*x0) * sin(P*pi*x1), P=1
// N = 16777216 rows, input [N,2] f32 interleaved, output [N,1] f32.
// Memory-bound: 192 MiB traffic -> ~32us floor at ~6.3 TB/s.
//
// Timed graph includes two 512-MiB harness poison fills (~158 us) — kernel
// portion is ~39 us. This round: UNROLL 4->8 (8 KB/wave of loads in flight,
// half the blocks) to close the ~39 -> ~32 us gap vs the streaming ceiling.
//
// sin(pi*x) computed as v_sin_f32(0.5*x) directly (v_sin takes revolutions):
// one exact mul (x in [0,1)) instead of __sinf's mul-by-pi + mul-by-1/2pi.

typedef float vf4 __attribute__((ext_vector_type(4)));
typedef float vf2 __attribute__((ext_vector_type(2)));

#define UNROLL 8
#define BLOCK 256

__device__ __forceinline__ float sinpi_f(float x) {
#if __has_builtin(__builtin_amdgcn_sinf)
    // sin(pi*x) == sin(2*pi * (x/2)); v_sin_f32 input is in revolutions.
    return __builtin_amdgcn_sinf(0.5f * x);
#else
    return __sinf(PI_F * x);
#endif
}

__global__ __launch_bounds__(BLOCK) void helm_kernel(
    const vf4* __restrict__ in,   // N/2 float4s (each = 2 rows)
    const float* __restrict__ a,
    vf2* __restrict__ out,        // N/2 float2s
    int n4)                       // N/2
{
    const int tid = threadIdx.x;
    const int base = blockIdx.x * (BLOCK * UNROLL) + tid;

    float av = a[0];
    float coef = av * av - 2.0f * (PI_F * PI_F);  // -pi^2 - pi^2 + a^2

    if (base + (UNROLL - 1) * BLOCK < n4) {
        // fast path: all UNROLL in range (block-uniform branch)
        vf4 v[UNROLL];
#pragma unroll
        for (int k = 0; k < UNROLL; ++k)
            v[k] = __builtin_nontemporal_load(&in[base + k * BLOCK]);

#pragma unroll
        for (int k = 0; k < UNROLL; ++k) {
            vf2 o;
            o.x = coef * sinpi_f(v[k].x) * sinpi_f(v[k].y);
            o.y = coef * sinpi_f(v[k].z) * sinpi_f(v[k].w);
            __builtin_nontemporal_store(o, &out[base + k * BLOCK]);
        }
    } else {
#pragma unroll
        for (int k = 0; k < UNROLL; ++k) {
            int idx = base + k * BLOCK;
            if (idx < n4) {
                vf4 v = __builtin_nontemporal_load(&in[idx]);
                vf2 o;
                o.x = coef * sinpi_f(v.x) * sinpi_f(v.y);
                o.y = coef * sinpi_f(v.z) * sinpi_f(v.w);
                __builtin_nontemporal_store(o, &out[idx]);
            }
        }
    }
}

extern "C" void kernel_launch(void* const* d_in, const int* in_sizes, int n_in,
                              void* d_out, int out_size, void* d_ws, size_t ws_size,
                              hipStream_t stream) {
    const vf4* in = (const vf4*)d_in[0];
    const float* a = (const float*)d_in[1];
    vf2* out = (vf2*)d_out;

    int n4 = out_size / 2;                       // 8388608 float4s / float2s
    int per_block = BLOCK * UNROLL;              // 2048
    int grid = (n4 + per_block - 1) / per_block; // 4096

    helm_kernel<<<grid, BLOCK, 0, stream>>>(in, a, out, n4);
}